// Round 11
// baseline (289.885 us; speedup 1.0000x reference)
//
#include <hip/hip_runtime.h>
#include <stdint.h>

// Problem constants (B,N,D,H fixed by setup_inputs)
#define B_  8
#define N_  768
#define D_  2048
#define H_  4
#define HN  192   // head width n = N/H

// padded global/LDS layouts for attention (conflict-free DMA-linear)
#define QROW 200          // K/Q row: 192 + 8 pad u16  -> 400 B (≡4 banks)
#define VROW 72           // V row: 64 + 8 pad u16     -> 144 B (≡4 banks)
#define KTILE_B 25600     // 64 * 400 B  (25 x 1024)
#define VTILE_B 27648     // 192 * 144 B (27 x 1024)

#define LOG2E 1.4426950408889634f
#define C2    2.8853901617f      // 2*log2e

typedef unsigned short u16;
typedef float    f32x4 __attribute__((ext_vector_type(4)));
typedef __bf16   bf16x8 __attribute__((ext_vector_type(8)));
typedef __bf16   bf16x4 __attribute__((ext_vector_type(4)));
typedef uint32_t u32x4 __attribute__((ext_vector_type(4)));
typedef uint32_t u32x2 __attribute__((ext_vector_type(2)));

// native bf16 convert: compiler pairs these into v_cvt_pk_bf16_f32 (RNE)
__device__ __forceinline__ u16 f2bf(float f) {
  return __builtin_bit_cast(u16, (__bf16)f);
}

// async global->LDS DMA, 16 B per lane; LDS dest = uniform base + lane*16
typedef const __attribute__((address_space(1))) void* gas_ptr;
typedef __attribute__((address_space(3))) void* las_ptr;
__device__ __forceinline__ void gld16(const void* g, void* l) {
  __builtin_amdgcn_global_load_lds((gas_ptr)g, (las_ptr)l, 16, 0, 0);
}

// ---------------------------------------------------------------------------
// Kernel 0: fused prep. Flat grid of 4000 blocks:
//   [0,3072)    transpose x (B,N,D) fp32 -> xt (B,D,N) bf16
//   [3072,3936) convert the three weight matrices fp32 -> bf16
//               (288 blk each; 8 floats/thread, bf16x8 16 B stores)
//   [3936,4000) zero the q2 accumulator (ws is poisoned 0xAA each launch)
// ---------------------------------------------------------------------------
__global__ __launch_bounds__(256) void prep(const float* __restrict__ x,
                                            const float* __restrict__ Wqk,
                                            const float* __restrict__ Wv,
                                            const float* __restrict__ Wout,
                                            u16* __restrict__ xt,
                                            u16* __restrict__ oqk,
                                            u16* __restrict__ ov,
                                            u16* __restrict__ oout,
                                            float* __restrict__ q2) {
  __shared__ float tile[64][65];
  const int bid = blockIdx.x;
  const int t   = threadIdx.x;
  if (bid < 3072) {
    const int d0 = (bid & 31) * 64;
    const int n0 = ((bid >> 5) % 12) * 64;
    const int b  = (bid >> 5) / 12;
    const int col = t & 63;
    const int rb  = (t >> 6) * 16;
    const float* src = x + ((size_t)b * N_ + n0) * D_ + d0;
    #pragma unroll
    for (int i = 0; i < 16; i++)
      tile[rb + i][col] = src[(size_t)(rb + i) * D_ + col];
    __syncthreads();
    u16* dst = xt + ((size_t)b * D_ + d0) * N_ + n0;
    #pragma unroll
    for (int i = 0; i < 16; i++)
      dst[(size_t)(rb + i) * N_ + col] = f2bf(tile[col][rb + i]);
  } else if (bid < 3936) {
    const int r   = bid - 3072;         // 0..863
    const int mat = r / 288;            // 288 blocks per matrix (N*N/2048)
    const float* src = (mat == 0) ? Wqk : ((mat == 1) ? Wv : Wout);
    u16*         dst = (mat == 0) ? oqk : ((mat == 1) ? ov : oout);
    const int i = ((r % 288) * 256 + t) * 8;
    f32x4 v0 = *(const f32x4*)(src + i);
    f32x4 v1 = *(const f32x4*)(src + i + 4);
    bf16x8 tmp;
    #pragma unroll
    for (int j = 0; j < 4; j++) { tmp[j] = (__bf16)v0[j]; tmp[4 + j] = (__bf16)v1[j]; }
    *(bf16x8*)(dst + i) = tmp;
  } else {
    const f32x4 fz = {0.f, 0.f, 0.f, 0.f};
    const int i = ((bid - 3936) * 256 + t) * 4;
    *(f32x4*)(q2 + i) = fz;
  }
}

// ---------------------------------------------------------------------------
// Kernel 1: fused QK/V GEMM, 128x128 tile, BK=64, __launch_bounds__(256, 3)
//   (3 blocks/CU, LDS-capped at 3 x 48 KB; the occupancy lever that moved
//   R10's GEMMs — cross-block overlap hides the barrier drain, m114).
//   qk computed SWAPPED (mfma(Bq, A)) -> direct bf16x4 stores to qkb rows.
//   v computed normal (mfma(A, Bv))  -> direct bf16x4 stores to vtb tiles.
//   q2[bh,d] += log2e * sum_j qk^2  (PRE-SCALED for attn's exp2 path).
// ---------------------------------------------------------------------------
__global__ __launch_bounds__(256, 3) void qkv_gemm(const u16* __restrict__ xt,
                                                   const u16* __restrict__ wqk,
                                                   const u16* __restrict__ wv,
                                                   u16* __restrict__ qkb,
                                                   u16* __restrict__ vtb,
                                                   float* __restrict__ q2) {
  const int b     = blockIdx.z;
  const int dtile = blockIdx.x;        // 128-wide d tile (0..15)
  const int d0    = dtile * 128;
  const int j0    = blockIdx.y * 128;  // 0..5
  const int tid  = threadIdx.x;
  const int wave = tid >> 6, lane = tid & 63;
  const int l15  = lane & 15, quad = lane >> 4;
  const int wm = wave >> 1, wn = wave & 1;

  __shared__ u16 At[128 * 64];   // 16 KB, linear (DMA dest), row stride 64
  __shared__ u16 Bq[128 * 64];
  __shared__ u16 Bv[128 * 64];

  const f32x4 fz = {0.f, 0.f, 0.f, 0.f};
  f32x4 accq[4][4];   // [nj][md]  C^T layout: row=j, col=d
  f32x4 accv[4][4];   // [mi][ni]  C   layout: row=d(=e), col=j
  #pragma unroll
  for (int i = 0; i < 4; i++)
    #pragma unroll
    for (int j = 0; j < 4; j++) { accq[i][j] = fz; accv[i][j] = fz; }

  const int srow  = tid >> 3;          // 0..31: row within 32-row chunk
  const int sbyte = (tid & 7) * 16;    // byte offset within the 128 B row seg
  const u16* ax = xt  + ((size_t)b * D_ + d0 + srow) * N_;
  const u16* bq = wqk + (size_t)(j0 + srow) * N_;
  const u16* bv = wv  + (size_t)(j0 + srow) * N_;

  for (int k0 = 0; k0 < N_; k0 += 64) {
    __syncthreads();
    #pragma unroll
    for (int c = 0; c < 4; c++) {
      gld16((const char*)(ax + (size_t)c * 32 * N_ + k0) + sbyte,
            (char*)At + c * 4096 + tid * 16);
      gld16((const char*)(bq + (size_t)c * 32 * N_ + k0) + sbyte,
            (char*)Bq + c * 4096 + tid * 16);
      gld16((const char*)(bv + (size_t)c * 32 * N_ + k0) + sbyte,
            (char*)Bv + c * 4096 + tid * 16);
    }
    __syncthreads();   // barrier's vmcnt(0) drains the DMA

    #pragma unroll
    for (int kk = 0; kk < 2; kk++) {
      bf16x8 Af[4];
      #pragma unroll
      for (int mi = 0; mi < 4; mi++)
        Af[mi] = *(const bf16x8*)&At[(wm * 64 + mi * 16 + l15) * 64 + kk * 32 + quad * 8];
      #pragma unroll
      for (int ni = 0; ni < 4; ni++) {
        bf16x8 Bqf = *(const bf16x8*)&Bq[(wn * 64 + ni * 16 + l15) * 64 + kk * 32 + quad * 8];
        bf16x8 Bvf = *(const bf16x8*)&Bv[(wn * 64 + ni * 16 + l15) * 64 + kk * 32 + quad * 8];
        #pragma unroll
        for (int mi = 0; mi < 4; mi++) {
          accq[ni][mi] = __builtin_amdgcn_mfma_f32_16x16x32_bf16(Bqf, Af[mi], accq[ni][mi], 0, 0, 0);
          accv[mi][ni] = __builtin_amdgcn_mfma_f32_16x16x32_bf16(Af[mi], Bvf, accv[mi][ni], 0, 0, 0);
        }
      }
    }
  }

  const int h_w  = (j0 + wn * 64) / HN;   // wave-uniform head
  const int jn_w = (j0 + wn * 64) % HN;
  const size_t bh = (size_t)b * H_ + h_w;

  // ---- q2 partial sums, pre-scaled by log2e for attn's exp2 ----
  #pragma unroll
  for (int md = 0; md < 4; md++) {
    float s = 0.f;
    #pragma unroll
    for (int nj = 0; nj < 4; nj++)
      #pragma unroll
      for (int r = 0; r < 4; r++) { float v = accq[nj][md][r]; s += v * v; }
    s += __shfl_xor(s, 16, 64);
    s += __shfl_xor(s, 32, 64);
    if (quad == 0)
      atomicAdd(&q2[bh * D_ + d0 + wm * 64 + md * 16 + l15], s * LOG2E);
  }

  // ---- qk direct store: lane holds 4 jn-consecutive values per fragment ----
  u16* qtbase = qkb + bh * (size_t)(D_ * QROW);
  #pragma unroll
  for (int md = 0; md < 4; md++) {
    const size_t dro = (size_t)(d0 + wm * 64 + md * 16 + l15) * QROW;
    #pragma unroll
    for (int nj = 0; nj < 4; nj++) {
      bf16x4 tmp;
      #pragma unroll
      for (int r = 0; r < 4; r++) tmp[r] = (__bf16)accq[nj][md][r];
      *(bf16x4*)(qtbase + dro + jn_w + nj * 16 + quad * 4) = tmp;
    }
  }

  // ---- v direct store: lane holds 4 e-consecutive values per fragment ----
  const int etile = dtile * 2 + wm;    // 64-wide e tile index (0..31)
  u16* vtbase = vtb + bh * (size_t)(32 * HN * VROW) + (size_t)etile * (HN * VROW);
  #pragma unroll
  for (int ni = 0; ni < 4; ni++) {
    const size_t jro = (size_t)(jn_w + ni * 16 + l15) * VROW;
    #pragma unroll
    for (int mi = 0; mi < 4; mi++) {
      bf16x4 tmp;
      #pragma unroll
      for (int r = 0; r < 4; r++) tmp[r] = (__bf16)accv[mi][ni][r];
      *(bf16x4*)(vtbase + jro + mi * 16 + quad * 4) = tmp;
    }
  }
}

// ---------------------------------------------------------------------------
// Kernel 2: fused attention v5 (verified best, ~121.5 us — frozen).
//   S^T = K·Q^T trick; exp2 path with pre-scaled q2; MFMA ones-rowsum;
//   setprio around MFMA clusters.  4 waves x 32 d-rows; grid 512, 2 blk/CU.
// ---------------------------------------------------------------------------
__global__ __launch_bounds__(256, 2) void attn_kernel(const u16* __restrict__ qkb,
                                                      const u16* __restrict__ vtb,
                                                      const float* __restrict__ q2,
                                                      u16* __restrict__ wbuf) {
  const int bid  = blockIdx.x;
  const int bh   = (bid & 7) * 4 + (bid >> 7);  // xcd*4 + sub: 4 bh per XCD
  const int dblk = (bid >> 3) & 15;             // 128-row block
  const int b = bh >> 2, h = bh & 3;
  const int tid  = threadIdx.x;
  const int wave = tid >> 6, lane = tid & 63;
  const int l15  = lane & 15, quad = lane >> 4;

  __shared__ u16 Klds[64 * QROW];        // 25.6 KB  [e][200]
  __shared__ u16 Vlds[HN * VROW];        // 27.6 KB  [jn][72]
  __shared__ u16 Plds[4][32][VROW];      // 18.4 KB  per-wave P [d][e(64)+pad]

  const u16* kg = qkb + (size_t)bh * (D_ * QROW);
  const u16* vg = vtb + (size_t)bh * (32 * HN * VROW);
  const float* q2g = q2 + (size_t)bh * D_;

  bf16x8 Qf[2][6];
  {
    const u16* qrow = kg + (size_t)(dblk * 128 + wave * 32 + l15) * QROW + quad * 8;
    #pragma unroll
    for (int nt = 0; nt < 2; nt++)
      #pragma unroll
      for (int f = 0; f < 6; f++)
        Qf[nt][f] = *(const bf16x8*)(qrow + (size_t)nt * 16 * QROW + f * 32);
  }
  float cd[2];
  cd[0] = q2g[dblk * 128 + wave * 32 + l15];
  cd[1] = q2g[dblk * 128 + wave * 32 + 16 + l15];

  bf16x8 OnesF;
  #pragma unroll
  for (int j = 0; j < 8; j++) OnesF[j] = (__bf16)1.0f;

  const f32x4 fz = {0.f, 0.f, 0.f, 0.f};
  f32x4 O[2][12];
  f32x4 Or[2];
  #pragma unroll
  for (int mt = 0; mt < 2; mt++) {
    Or[mt] = fz;
    #pragma unroll
    for (int c = 0; c < 12; c++) O[mt][c] = fz;
  }

  for (int t = 0; t < 32; t++) {
    __syncthreads();   // all waves done reading previous K/V
    {
      const char* ks = (const char*)kg + (size_t)t * KTILE_B;
      char* kd = (char*)Klds;
      for (int c = wave; c < 25; c += 4)
        gld16(ks + c * 1024 + lane * 16, kd + c * 1024 + lane * 16);
      const char* vs = (const char*)vg + (size_t)t * VTILE_B;
      char* vd = (char*)Vlds;
      for (int c = wave; c < 27; c += 4)
        gld16(vs + c * 1024 + lane * 16, vd + c * 1024 + lane * 16);
    }
    __syncthreads();   // barrier's vmcnt(0) drains the DMA

    #pragma unroll
    for (int et = 0; et < 4; et++) {
      bf16x8 Kf[6];
      #pragma unroll
      for (int f = 0; f < 6; f++)
        Kf[f] = *(const bf16x8*)&Klds[(et * 16 + l15) * QROW + f * 32 + quad * 8];
      f32x4 S0 = fz, S1 = fz;
      __builtin_amdgcn_s_setprio(1);
      #pragma unroll
      for (int f = 0; f < 6; f++) {
        S0 = __builtin_amdgcn_mfma_f32_16x16x32_bf16(Kf[f], Qf[0][f], S0, 0, 0, 0);
        S1 = __builtin_amdgcn_mfma_f32_16x16x32_bf16(Kf[f], Qf[1][f], S1, 0, 0, 0);
      }
      __builtin_amdgcn_s_setprio(0);
      const f32x4 ce = *(const f32x4*)&q2g[t * 64 + et * 16 + quad * 4];
      bf16x4 pb0, pb1;
      #pragma unroll
      for (int r = 0; r < 4; r++) {
        float p0 = __builtin_amdgcn_exp2f(__builtin_fmaf(S0[r], C2, -(ce[r] + cd[0])));
        float p1 = __builtin_amdgcn_exp2f(__builtin_fmaf(S1[r], C2, -(ce[r] + cd[1])));
        pb0[r] = (__bf16)p0;
        pb1[r] = (__bf16)p1;
      }
      *(bf16x4*)&Plds[wave][l15][et * 16 + quad * 4]      = pb0;
      *(bf16x4*)&Plds[wave][16 + l15][et * 16 + quad * 4] = pb1;
    }

    #pragma unroll
    for (int kk = 0; kk < 2; kk++) {
      bf16x8 Pf0 = *(const bf16x8*)&Plds[wave][l15][kk * 32 + quad * 8];
      bf16x8 Pf1 = *(const bf16x8*)&Plds[wave][16 + l15][kk * 32 + quad * 8];
      __builtin_amdgcn_s_setprio(1);
      #pragma unroll
      for (int c = 0; c < 12; c++) {
        bf16x8 Vf = *(const bf16x8*)&Vlds[(c * 16 + l15) * VROW + kk * 32 + quad * 8];
        O[0][c] = __builtin_amdgcn_mfma_f32_16x16x32_bf16(Pf0, Vf, O[0][c], 0, 0, 0);
        O[1][c] = __builtin_amdgcn_mfma_f32_16x16x32_bf16(Pf1, Vf, O[1][c], 0, 0, 0);
      }
      Or[0] = __builtin_amdgcn_mfma_f32_16x16x32_bf16(Pf0, OnesF, Or[0], 0, 0, 0);
      Or[1] = __builtin_amdgcn_mfma_f32_16x16x32_bf16(Pf1, OnesF, Or[1], 0, 0, 0);
      __builtin_amdgcn_s_setprio(0);
    }
  }

  #pragma unroll
  for (int mt = 0; mt < 2; mt++)
    #pragma unroll
    for (int r = 0; r < 4; r++) {
      const float inv = __builtin_amdgcn_rcpf(Or[mt][r]);
      const int d = dblk * 128 + wave * 32 + mt * 16 + quad * 4 + r;
      u16* wrow = wbuf + ((size_t)b * D_ + d) * N_ + h * HN;
      #pragma unroll
      for (int c = 0; c < 12; c++)
        wrow[c * 16 + l15] = f2bf(O[mt][c][r] * inv);
    }
}

// ---------------------------------------------------------------------------
// Kernel 3: out GEMM, 128x128 tile, BK=64, __launch_bounds__(256, 4):
//   4 blocks/CU (LDS 4 x 32 KB = 128 KB; acc=64 + ~40 live VGPR fits the
//   128/wave cap at 16 waves/CU).  Extends R10's occupancy win.
//   out[b,i,d] = sum_j w[b,d,j]*Wout[i,j] (fp32); direct f32x4 stores.
// ---------------------------------------------------------------------------
__global__ __launch_bounds__(256, 4) void out_gemm(const u16* __restrict__ wbuf,
                                                   const u16* __restrict__ wout,
                                                   float* __restrict__ outp) {
  const int b  = blockIdx.z;
  const int d0 = blockIdx.x * 128;
  const int i0 = blockIdx.y * 128;
  const int tid  = threadIdx.x;
  const int wave = tid >> 6, lane = tid & 63;
  const int l15  = lane & 15, quad = lane >> 4;
  const int wm = wave >> 1, wn = wave & 1;

  __shared__ u16 At[128 * 64];   // 16 KB, linear (DMA dest), row stride 64
  __shared__ u16 Bt[128 * 64];

  const f32x4 fz = {0.f, 0.f, 0.f, 0.f};
  f32x4 acc[4][4];   // [mi][ni]  C layout: row=d, col=i
  #pragma unroll
  for (int i = 0; i < 4; i++)
    #pragma unroll
    for (int j = 0; j < 4; j++) acc[i][j] = fz;

  const int srow  = tid >> 3;          // 0..31
  const int sbyte = (tid & 7) * 16;
  const u16* ax = wbuf + ((size_t)b * D_ + d0 + srow) * N_;
  const u16* bw = wout + (size_t)(i0 + srow) * N_;

  for (int k0 = 0; k0 < N_; k0 += 64) {
    __syncthreads();
    #pragma unroll
    for (int c = 0; c < 4; c++) {
      gld16((const char*)(ax + (size_t)c * 32 * N_ + k0) + sbyte,
            (char*)At + c * 4096 + tid * 16);
      gld16((const char*)(bw + (size_t)c * 32 * N_ + k0) + sbyte,
            (char*)Bt + c * 4096 + tid * 16);
    }
    __syncthreads();

    #pragma unroll
    for (int kk = 0; kk < 2; kk++) {
      bf16x8 Af[4];
      #pragma unroll
      for (int mi = 0; mi < 4; mi++)
        Af[mi] = *(const bf16x8*)&At[(wm * 64 + mi * 16 + l15) * 64 + kk * 32 + quad * 8];
      #pragma unroll
      for (int ni = 0; ni < 4; ni++) {
        bf16x8 Bf = *(const bf16x8*)&Bt[(wn * 64 + ni * 16 + l15) * 64 + kk * 32 + quad * 8];
        #pragma unroll
        for (int mi = 0; mi < 4; mi++)
          acc[mi][ni] = __builtin_amdgcn_mfma_f32_16x16x32_bf16(Af[mi], Bf, acc[mi][ni], 0, 0, 0);
      }
    }
  }

  // direct store: lane (l15,quad) fragment (mi,ni) -> out[b][i0+wn*64+ni*16+l15]
  //               [d0+wm*64+mi*16+quad*4 .. +3], f32x4 (16B aligned)
  #pragma unroll
  for (int ni = 0; ni < 4; ni++) {
    float* orow = outp + ((size_t)b * N_ + i0 + wn * 64 + ni * 16 + l15) * D_
                + d0 + wm * 64 + quad * 4;
    #pragma unroll
    for (int mi = 0; mi < 4; mi++)
      *(f32x4*)(orow + mi * 16) = acc[mi][ni];
  }
}

// ---------------------------------------------------------------------------
extern "C" void kernel_launch(void* const* d_in, const int* in_sizes, int n_in,
                              void* d_out, int out_size, void* d_ws, size_t ws_size,
                              hipStream_t stream) {
  (void)in_sizes; (void)n_in; (void)out_size; (void)ws_size;
  const float* x    = (const float*)d_in[0];
  const float* Wqk  = (const float*)d_in[1];
  const float* Wv   = (const float*)d_in[2];
  const float* Wout = (const float*)d_in[3];
  float* outp = (float*)d_out;

  // Workspace layout (~83.5 MB total; all offsets 16B-aligned)
  char* ws = (char*)d_ws;
  size_t off = 0;
  u16* xt   = (u16*)(ws + off); off += (size_t)B_ * D_ * N_ * 2;          // 25.2 MB
  u16* qkb  = (u16*)(ws + off); off += (size_t)B_ * H_ * D_ * QROW * 2;   // 26.2 MB
  u16* vtb  = (u16*)(ws + off); off += (size_t)B_ * H_ * 32 * HN * VROW * 2; // 28.3 MB
  float* q2 = (float*)(ws + off); off += (size_t)B_ * H_ * D_ * 4;        // 256 KB
  u16* wqk_bf  = (u16*)(ws + off); off += (size_t)N_ * N_ * 2;
  u16* wv_bf   = (u16*)(ws + off); off += (size_t)N_ * N_ * 2;
  u16* wout_bf = (u16*)(ws + off); off += (size_t)N_ * N_ * 2;
  u16* wbuf = xt;   // xt dead after qkv_gemm; reuse for attention output

  prep<<<dim3(4000), 256, 0, stream>>>(x, Wqk, Wv, Wout, xt, wqk_bf, wv_bf, wout_bf, q2);
  qkv_gemm<<<dim3(D_ / 128, N_ / 128, B_), 256, 0, stream>>>(xt, wqk_bf, wv_bf, qkb, vtb, q2);
  attn_kernel<<<dim3((D_ / 128) * B_ * H_), 256, 0, stream>>>(qkb, vtb, q2, wbuf);
  out_gemm<<<dim3(D_ / 128, N_ / 128, B_), 256, 0, stream>>>(wbuf, wout_bf, outp);
}

// Round 12
// 284.813 us; speedup vs baseline: 1.0178x; 1.0178x over previous
//
#include <hip/hip_runtime.h>
#include <stdint.h>

// Problem constants (B,N,D,H fixed by setup_inputs)
#define B_  8
#define N_  768
#define D_  2048
#define H_  4
#define HN  192   // head width n = N/H

// padded global/LDS layouts for attention (conflict-free DMA-linear)
#define QROW 200          // K/Q row: 192 + 8 pad u16  -> 400 B (≡4 banks)
#define VROW 72           // V row: 64 + 8 pad u16     -> 144 B (≡4 banks)
#define KTILE_B 25600     // 64 * 400 B  (25 x 1024)
#define VTILE_B 27648     // 192 * 144 B (27 x 1024)

#define LOG2E 1.4426950408889634f
#define C2    2.8853901617f      // 2*log2e

typedef unsigned short u16;
typedef float    f32x4 __attribute__((ext_vector_type(4)));
typedef __bf16   bf16x8 __attribute__((ext_vector_type(8)));
typedef __bf16   bf16x4 __attribute__((ext_vector_type(4)));
typedef uint32_t u32x4 __attribute__((ext_vector_type(4)));
typedef uint32_t u32x2 __attribute__((ext_vector_type(2)));

// native bf16 convert: compiler pairs these into v_cvt_pk_bf16_f32 (RNE)
__device__ __forceinline__ u16 f2bf(float f) {
  return __builtin_bit_cast(u16, (__bf16)f);
}

// async global->LDS DMA, 16 B per lane; LDS dest = uniform base + lane*16
typedef const __attribute__((address_space(1))) void* gas_ptr;
typedef __attribute__((address_space(3))) void* las_ptr;
__device__ __forceinline__ void gld16(const void* g, void* l) {
  __builtin_amdgcn_global_load_lds((gas_ptr)g, (las_ptr)l, 16, 0, 0);
}

// ---------------------------------------------------------------------------
// Kernel 0: fused prep. Flat grid of 4864 blocks (R10 config — R11's 8-wide
//   cvt variant reverted, it cost ~1-2 us of launch parallelism):
//   [0,3072)    transpose x (B,N,D) fp32 -> xt (B,D,N) bf16
//   [3072,4800) convert the three weight matrices fp32 -> bf16 (576 blk each)
//   [4800,4864) zero the q2 accumulator (ws is poisoned 0xAA each launch)
// ---------------------------------------------------------------------------
__global__ __launch_bounds__(256) void prep(const float* __restrict__ x,
                                            const float* __restrict__ Wqk,
                                            const float* __restrict__ Wv,
                                            const float* __restrict__ Wout,
                                            u16* __restrict__ xt,
                                            u16* __restrict__ oqk,
                                            u16* __restrict__ ov,
                                            u16* __restrict__ oout,
                                            float* __restrict__ q2) {
  __shared__ float tile[64][65];
  const int bid = blockIdx.x;
  const int t   = threadIdx.x;
  if (bid < 3072) {
    const int d0 = (bid & 31) * 64;
    const int n0 = ((bid >> 5) % 12) * 64;
    const int b  = (bid >> 5) / 12;
    const int col = t & 63;
    const int rb  = (t >> 6) * 16;
    const float* src = x + ((size_t)b * N_ + n0) * D_ + d0;
    #pragma unroll
    for (int i = 0; i < 16; i++)
      tile[rb + i][col] = src[(size_t)(rb + i) * D_ + col];
    __syncthreads();
    u16* dst = xt + ((size_t)b * D_ + d0) * N_ + n0;
    #pragma unroll
    for (int i = 0; i < 16; i++)
      dst[(size_t)(rb + i) * N_ + col] = f2bf(tile[col][rb + i]);
  } else if (bid < 4800) {
    const int r   = bid - 3072;         // 0..1727
    const int mat = r / 576;            // 576 blocks per matrix (N*N/1024)
    const float* src = (mat == 0) ? Wqk : ((mat == 1) ? Wv : Wout);
    u16*         dst = (mat == 0) ? oqk : ((mat == 1) ? ov : oout);
    const int i = ((r % 576) * 256 + t) * 4;
    f32x4 v = *(const f32x4*)(src + i);
    bf16x4 tmp;
    #pragma unroll
    for (int j = 0; j < 4; j++) tmp[j] = (__bf16)v[j];
    *(bf16x4*)(dst + i) = tmp;
  } else {
    const f32x4 fz = {0.f, 0.f, 0.f, 0.f};
    const int i = ((bid - 4800) * 256 + t) * 4;
    *(f32x4*)(q2 + i) = fz;
  }
}

// ---------------------------------------------------------------------------
// Kernel 1: fused QK/V GEMM, 128x128 tile, BK=64, __launch_bounds__(256, 3)
//   (3 blocks/CU, LDS-capped at 3 x 48 KB; the occupancy lever that moved
//   R10's GEMMs — cross-block overlap hides the barrier drain, m114).
//   qk computed SWAPPED (mfma(Bq, A)) -> direct bf16x4 stores to qkb rows.
//   v computed normal (mfma(A, Bv))  -> direct bf16x4 stores to vtb tiles.
//   q2[bh,d] += log2e * sum_j qk^2  (PRE-SCALED for attn's exp2 path).
// ---------------------------------------------------------------------------
__global__ __launch_bounds__(256, 3) void qkv_gemm(const u16* __restrict__ xt,
                                                   const u16* __restrict__ wqk,
                                                   const u16* __restrict__ wv,
                                                   u16* __restrict__ qkb,
                                                   u16* __restrict__ vtb,
                                                   float* __restrict__ q2) {
  const int b     = blockIdx.z;
  const int dtile = blockIdx.x;        // 128-wide d tile (0..15)
  const int d0    = dtile * 128;
  const int j0    = blockIdx.y * 128;  // 0..5
  const int tid  = threadIdx.x;
  const int wave = tid >> 6, lane = tid & 63;
  const int l15  = lane & 15, quad = lane >> 4;
  const int wm = wave >> 1, wn = wave & 1;

  __shared__ u16 At[128 * 64];   // 16 KB, linear (DMA dest), row stride 64
  __shared__ u16 Bq[128 * 64];
  __shared__ u16 Bv[128 * 64];

  const f32x4 fz = {0.f, 0.f, 0.f, 0.f};
  f32x4 accq[4][4];   // [nj][md]  C^T layout: row=j, col=d
  f32x4 accv[4][4];   // [mi][ni]  C   layout: row=d(=e), col=j
  #pragma unroll
  for (int i = 0; i < 4; i++)
    #pragma unroll
    for (int j = 0; j < 4; j++) { accq[i][j] = fz; accv[i][j] = fz; }

  const int srow  = tid >> 3;          // 0..31: row within 32-row chunk
  const int sbyte = (tid & 7) * 16;    // byte offset within the 128 B row seg
  const u16* ax = xt  + ((size_t)b * D_ + d0 + srow) * N_;
  const u16* bq = wqk + (size_t)(j0 + srow) * N_;
  const u16* bv = wv  + (size_t)(j0 + srow) * N_;

  for (int k0 = 0; k0 < N_; k0 += 64) {
    __syncthreads();
    #pragma unroll
    for (int c = 0; c < 4; c++) {
      gld16((const char*)(ax + (size_t)c * 32 * N_ + k0) + sbyte,
            (char*)At + c * 4096 + tid * 16);
      gld16((const char*)(bq + (size_t)c * 32 * N_ + k0) + sbyte,
            (char*)Bq + c * 4096 + tid * 16);
      gld16((const char*)(bv + (size_t)c * 32 * N_ + k0) + sbyte,
            (char*)Bv + c * 4096 + tid * 16);
    }
    __syncthreads();   // barrier's vmcnt(0) drains the DMA

    #pragma unroll
    for (int kk = 0; kk < 2; kk++) {
      bf16x8 Af[4];
      #pragma unroll
      for (int mi = 0; mi < 4; mi++)
        Af[mi] = *(const bf16x8*)&At[(wm * 64 + mi * 16 + l15) * 64 + kk * 32 + quad * 8];
      #pragma unroll
      for (int ni = 0; ni < 4; ni++) {
        bf16x8 Bqf = *(const bf16x8*)&Bq[(wn * 64 + ni * 16 + l15) * 64 + kk * 32 + quad * 8];
        bf16x8 Bvf = *(const bf16x8*)&Bv[(wn * 64 + ni * 16 + l15) * 64 + kk * 32 + quad * 8];
        #pragma unroll
        for (int mi = 0; mi < 4; mi++) {
          accq[ni][mi] = __builtin_amdgcn_mfma_f32_16x16x32_bf16(Bqf, Af[mi], accq[ni][mi], 0, 0, 0);
          accv[mi][ni] = __builtin_amdgcn_mfma_f32_16x16x32_bf16(Af[mi], Bvf, accv[mi][ni], 0, 0, 0);
        }
      }
    }
  }

  const int h_w  = (j0 + wn * 64) / HN;   // wave-uniform head
  const int jn_w = (j0 + wn * 64) % HN;
  const size_t bh = (size_t)b * H_ + h_w;

  // ---- q2 partial sums, pre-scaled by log2e for attn's exp2 ----
  #pragma unroll
  for (int md = 0; md < 4; md++) {
    float s = 0.f;
    #pragma unroll
    for (int nj = 0; nj < 4; nj++)
      #pragma unroll
      for (int r = 0; r < 4; r++) { float v = accq[nj][md][r]; s += v * v; }
    s += __shfl_xor(s, 16, 64);
    s += __shfl_xor(s, 32, 64);
    if (quad == 0)
      atomicAdd(&q2[bh * D_ + d0 + wm * 64 + md * 16 + l15], s * LOG2E);
  }

  // ---- qk direct store: lane holds 4 jn-consecutive values per fragment ----
  u16* qtbase = qkb + bh * (size_t)(D_ * QROW);
  #pragma unroll
  for (int md = 0; md < 4; md++) {
    const size_t dro = (size_t)(d0 + wm * 64 + md * 16 + l15) * QROW;
    #pragma unroll
    for (int nj = 0; nj < 4; nj++) {
      bf16x4 tmp;
      #pragma unroll
      for (int r = 0; r < 4; r++) tmp[r] = (__bf16)accq[nj][md][r];
      *(bf16x4*)(qtbase + dro + jn_w + nj * 16 + quad * 4) = tmp;
    }
  }

  // ---- v direct store: lane holds 4 e-consecutive values per fragment ----
  const int etile = dtile * 2 + wm;    // 64-wide e tile index (0..31)
  u16* vtbase = vtb + bh * (size_t)(32 * HN * VROW) + (size_t)etile * (HN * VROW);
  #pragma unroll
  for (int ni = 0; ni < 4; ni++) {
    const size_t jro = (size_t)(jn_w + ni * 16 + l15) * VROW;
    #pragma unroll
    for (int mi = 0; mi < 4; mi++) {
      bf16x4 tmp;
      #pragma unroll
      for (int r = 0; r < 4; r++) tmp[r] = (__bf16)accv[mi][ni][r];
      *(bf16x4*)(vtbase + jro + mi * 16 + quad * 4) = tmp;
    }
  }
}

// ---------------------------------------------------------------------------
// Kernel 2: fused attention v5 (verified best, ~121.5 us — frozen).
//   S^T = K·Q^T trick; exp2 path with pre-scaled q2; MFMA ones-rowsum;
//   setprio around MFMA clusters.  4 waves x 32 d-rows; grid 512, 2 blk/CU.
// ---------------------------------------------------------------------------
__global__ __launch_bounds__(256, 2) void attn_kernel(const u16* __restrict__ qkb,
                                                      const u16* __restrict__ vtb,
                                                      const float* __restrict__ q2,
                                                      u16* __restrict__ wbuf) {
  const int bid  = blockIdx.x;
  const int bh   = (bid & 7) * 4 + (bid >> 7);  // xcd*4 + sub: 4 bh per XCD
  const int dblk = (bid >> 3) & 15;             // 128-row block
  const int b = bh >> 2, h = bh & 3;
  const int tid  = threadIdx.x;
  const int wave = tid >> 6, lane = tid & 63;
  const int l15  = lane & 15, quad = lane >> 4;

  __shared__ u16 Klds[64 * QROW];        // 25.6 KB  [e][200]
  __shared__ u16 Vlds[HN * VROW];        // 27.6 KB  [jn][72]
  __shared__ u16 Plds[4][32][VROW];      // 18.4 KB  per-wave P [d][e(64)+pad]

  const u16* kg = qkb + (size_t)bh * (D_ * QROW);
  const u16* vg = vtb + (size_t)bh * (32 * HN * VROW);
  const float* q2g = q2 + (size_t)bh * D_;

  bf16x8 Qf[2][6];
  {
    const u16* qrow = kg + (size_t)(dblk * 128 + wave * 32 + l15) * QROW + quad * 8;
    #pragma unroll
    for (int nt = 0; nt < 2; nt++)
      #pragma unroll
      for (int f = 0; f < 6; f++)
        Qf[nt][f] = *(const bf16x8*)(qrow + (size_t)nt * 16 * QROW + f * 32);
  }
  float cd[2];
  cd[0] = q2g[dblk * 128 + wave * 32 + l15];
  cd[1] = q2g[dblk * 128 + wave * 32 + 16 + l15];

  bf16x8 OnesF;
  #pragma unroll
  for (int j = 0; j < 8; j++) OnesF[j] = (__bf16)1.0f;

  const f32x4 fz = {0.f, 0.f, 0.f, 0.f};
  f32x4 O[2][12];
  f32x4 Or[2];
  #pragma unroll
  for (int mt = 0; mt < 2; mt++) {
    Or[mt] = fz;
    #pragma unroll
    for (int c = 0; c < 12; c++) O[mt][c] = fz;
  }

  for (int t = 0; t < 32; t++) {
    __syncthreads();   // all waves done reading previous K/V
    {
      const char* ks = (const char*)kg + (size_t)t * KTILE_B;
      char* kd = (char*)Klds;
      for (int c = wave; c < 25; c += 4)
        gld16(ks + c * 1024 + lane * 16, kd + c * 1024 + lane * 16);
      const char* vs = (const char*)vg + (size_t)t * VTILE_B;
      char* vd = (char*)Vlds;
      for (int c = wave; c < 27; c += 4)
        gld16(vs + c * 1024 + lane * 16, vd + c * 1024 + lane * 16);
    }
    __syncthreads();   // barrier's vmcnt(0) drains the DMA

    #pragma unroll
    for (int et = 0; et < 4; et++) {
      bf16x8 Kf[6];
      #pragma unroll
      for (int f = 0; f < 6; f++)
        Kf[f] = *(const bf16x8*)&Klds[(et * 16 + l15) * QROW + f * 32 + quad * 8];
      f32x4 S0 = fz, S1 = fz;
      __builtin_amdgcn_s_setprio(1);
      #pragma unroll
      for (int f = 0; f < 6; f++) {
        S0 = __builtin_amdgcn_mfma_f32_16x16x32_bf16(Kf[f], Qf[0][f], S0, 0, 0, 0);
        S1 = __builtin_amdgcn_mfma_f32_16x16x32_bf16(Kf[f], Qf[1][f], S1, 0, 0, 0);
      }
      __builtin_amdgcn_s_setprio(0);
      const f32x4 ce = *(const f32x4*)&q2g[t * 64 + et * 16 + quad * 4];
      bf16x4 pb0, pb1;
      #pragma unroll
      for (int r = 0; r < 4; r++) {
        float p0 = __builtin_amdgcn_exp2f(__builtin_fmaf(S0[r], C2, -(ce[r] + cd[0])));
        float p1 = __builtin_amdgcn_exp2f(__builtin_fmaf(S1[r], C2, -(ce[r] + cd[1])));
        pb0[r] = (__bf16)p0;
        pb1[r] = (__bf16)p1;
      }
      *(bf16x4*)&Plds[wave][l15][et * 16 + quad * 4]      = pb0;
      *(bf16x4*)&Plds[wave][16 + l15][et * 16 + quad * 4] = pb1;
    }

    #pragma unroll
    for (int kk = 0; kk < 2; kk++) {
      bf16x8 Pf0 = *(const bf16x8*)&Plds[wave][l15][kk * 32 + quad * 8];
      bf16x8 Pf1 = *(const bf16x8*)&Plds[wave][16 + l15][kk * 32 + quad * 8];
      __builtin_amdgcn_s_setprio(1);
      #pragma unroll
      for (int c = 0; c < 12; c++) {
        bf16x8 Vf = *(const bf16x8*)&Vlds[(c * 16 + l15) * VROW + kk * 32 + quad * 8];
        O[0][c] = __builtin_amdgcn_mfma_f32_16x16x32_bf16(Pf0, Vf, O[0][c], 0, 0, 0);
        O[1][c] = __builtin_amdgcn_mfma_f32_16x16x32_bf16(Pf1, Vf, O[1][c], 0, 0, 0);
      }
      Or[0] = __builtin_amdgcn_mfma_f32_16x16x32_bf16(Pf0, OnesF, Or[0], 0, 0, 0);
      Or[1] = __builtin_amdgcn_mfma_f32_16x16x32_bf16(Pf1, OnesF, Or[1], 0, 0, 0);
      __builtin_amdgcn_s_setprio(0);
    }
  }

  #pragma unroll
  for (int mt = 0; mt < 2; mt++)
    #pragma unroll
    for (int r = 0; r < 4; r++) {
      const float inv = __builtin_amdgcn_rcpf(Or[mt][r]);
      const int d = dblk * 128 + wave * 32 + mt * 16 + quad * 4 + r;
      u16* wrow = wbuf + ((size_t)b * D_ + d) * N_ + h * HN;
      #pragma unroll
      for (int c = 0; c < 12; c++)
        wrow[c * 16 + l15] = f2bf(O[mt][c][r] * inv);
    }
}

// ---------------------------------------------------------------------------
// Kernel 3: out GEMM, 128x128 tile, BK=64, __launch_bounds__(256, 3)
//   (R10 config — R11's (256,4) reverted: 128 VGPR/wave cap pinched the
//   fp32 epilogue and regressed).  out[b,i,d] = sum_j w[b,d,j]*Wout[i,j];
//   normal C layout -> direct f32x4 stores.
// ---------------------------------------------------------------------------
__global__ __launch_bounds__(256, 3) void out_gemm(const u16* __restrict__ wbuf,
                                                   const u16* __restrict__ wout,
                                                   float* __restrict__ outp) {
  const int b  = blockIdx.z;
  const int d0 = blockIdx.x * 128;
  const int i0 = blockIdx.y * 128;
  const int tid  = threadIdx.x;
  const int wave = tid >> 6, lane = tid & 63;
  const int l15  = lane & 15, quad = lane >> 4;
  const int wm = wave >> 1, wn = wave & 1;

  __shared__ u16 At[128 * 64];   // 16 KB, linear (DMA dest), row stride 64
  __shared__ u16 Bt[128 * 64];

  const f32x4 fz = {0.f, 0.f, 0.f, 0.f};
  f32x4 acc[4][4];   // [mi][ni]  C layout: row=d, col=i
  #pragma unroll
  for (int i = 0; i < 4; i++)
    #pragma unroll
    for (int j = 0; j < 4; j++) acc[i][j] = fz;

  const int srow  = tid >> 3;          // 0..31
  const int sbyte = (tid & 7) * 16;
  const u16* ax = wbuf + ((size_t)b * D_ + d0 + srow) * N_;
  const u16* bw = wout + (size_t)(i0 + srow) * N_;

  for (int k0 = 0; k0 < N_; k0 += 64) {
    __syncthreads();
    #pragma unroll
    for (int c = 0; c < 4; c++) {
      gld16((const char*)(ax + (size_t)c * 32 * N_ + k0) + sbyte,
            (char*)At + c * 4096 + tid * 16);
      gld16((const char*)(bw + (size_t)c * 32 * N_ + k0) + sbyte,
            (char*)Bt + c * 4096 + tid * 16);
    }
    __syncthreads();

    #pragma unroll
    for (int kk = 0; kk < 2; kk++) {
      bf16x8 Af[4];
      #pragma unroll
      for (int mi = 0; mi < 4; mi++)
        Af[mi] = *(const bf16x8*)&At[(wm * 64 + mi * 16 + l15) * 64 + kk * 32 + quad * 8];
      #pragma unroll
      for (int ni = 0; ni < 4; ni++) {
        bf16x8 Bf = *(const bf16x8*)&Bt[(wn * 64 + ni * 16 + l15) * 64 + kk * 32 + quad * 8];
        #pragma unroll
        for (int mi = 0; mi < 4; mi++)
          acc[mi][ni] = __builtin_amdgcn_mfma_f32_16x16x32_bf16(Af[mi], Bf, acc[mi][ni], 0, 0, 0);
      }
    }
  }

  // direct store: lane (l15,quad) fragment (mi,ni) -> out[b][i0+wn*64+ni*16+l15]
  //               [d0+wm*64+mi*16+quad*4 .. +3], f32x4 (16B aligned)
  #pragma unroll
  for (int ni = 0; ni < 4; ni++) {
    float* orow = outp + ((size_t)b * N_ + i0 + wn * 64 + ni * 16 + l15) * D_
                + d0 + wm * 64 + quad * 4;
    #pragma unroll
    for (int mi = 0; mi < 4; mi++)
      *(f32x4*)(orow + mi * 16) = acc[mi][ni];
  }
}

// ---------------------------------------------------------------------------
extern "C" void kernel_launch(void* const* d_in, const int* in_sizes, int n_in,
                              void* d_out, int out_size, void* d_ws, size_t ws_size,
                              hipStream_t stream) {
  (void)in_sizes; (void)n_in; (void)out_size; (void)ws_size;
  const float* x    = (const float*)d_in[0];
  const float* Wqk  = (const float*)d_in[1];
  const float* Wv   = (const float*)d_in[2];
  const float* Wout = (const float*)d_in[3];
  float* outp = (float*)d_out;

  // Workspace layout (~83.5 MB total; all offsets 16B-aligned)
  char* ws = (char*)d_ws;
  size_t off = 0;
  u16* xt   = (u16*)(ws + off); off += (size_t)B_ * D_ * N_ * 2;          // 25.2 MB
  u16* qkb  = (u16*)(ws + off); off += (size_t)B_ * H_ * D_ * QROW * 2;   // 26.2 MB
  u16* vtb  = (u16*)(ws + off); off += (size_t)B_ * H_ * 32 * HN * VROW * 2; // 28.3 MB
  float* q2 = (float*)(ws + off); off += (size_t)B_ * H_ * D_ * 4;        // 256 KB
  u16* wqk_bf  = (u16*)(ws + off); off += (size_t)N_ * N_ * 2;
  u16* wv_bf   = (u16*)(ws + off); off += (size_t)N_ * N_ * 2;
  u16* wout_bf = (u16*)(ws + off); off += (size_t)N_ * N_ * 2;
  u16* wbuf = xt;   // xt dead after qkv_gemm; reuse for attention output

  prep<<<dim3(4864), 256, 0, stream>>>(x, Wqk, Wv, Wout, xt, wqk_bf, wv_bf, wout_bf, q2);
  qkv_gemm<<<dim3(D_ / 128, N_ / 128, B_), 256, 0, stream>>>(xt, wqk_bf, wv_bf, qkb, vtb, q2);
  attn_kernel<<<dim3((D_ / 128) * B_ * H_), 256, 0, stream>>>(qkb, vtb, q2, wbuf);
  out_gemm<<<dim3(D_ / 128, N_ / 128, B_), 256, 0, stream>>>(wbuf, wout_bf, outp);
}